// Round 9
// baseline (84.320 us; speedup 1.0000x reference)
//
#include <hip/hip_runtime.h>
#include <hip/hip_fp16.h>
#include <stdint.h>

// out[c,b,g] = sum_{s<8} prod_{l<3} x[b, I[c,g,s,l]]
#define Cc 16
#define Gg 8192
#define Ss 8
#define Ll 3
#define Bb 32

#define TGB 64             // g's per block (256 thr = 64 g x 4 parts)

// --- Kernel A: xf[g] = 32 f16 (b ascending), one 64 B row per g, 64 B aligned.
// A random row = exactly ONE cache line, fully consumed by 4 lanes x dwordx4.
__global__ __launch_bounds__(256) void build_xf(const float* __restrict__ x,
                                                uint2* __restrict__ xf2) {
    __shared__ float t[32][33];
    const int g0 = blockIdx.x * 32;
    const int tx = threadIdx.x & 31, ty = threadIdx.x >> 5;
    #pragma unroll
    for (int r = 0; r < 4; ++r)
        t[8 * r + ty][tx] = x[(size_t)(8 * r + ty) * Gg + g0 + tx];  // coalesced
    __syncthreads();
    const int q = threadIdx.x & 7, gl = threadIdx.x >> 3;
    __half2 h0 = __floats2half2_rn(t[4 * q + 0][gl], t[4 * q + 1][gl]);
    __half2 h1 = __floats2half2_rn(t[4 * q + 2][gl], t[4 * q + 3][gl]);
    uint2 o = { *(const uint32_t*)&h0, *(const uint32_t*)&h1 };
    xf2[(size_t)(g0 + gl) * 8 + q] = o;               // 64 B runs, coalesced
}

// --- Kernel B: pure-TCP gather. Lane = (g = tid>>2, part = tid&3); a wave's
// gather instr = 16 random g-rows x 4 parts = 16 distinct 64 B lines, fully
// used (the R3-measured 56 cyc/instr regime; random-LDS measured ~2x worse in
// R6-R8, so no value staging at all). Indices staged once per block into a
// tiny LDS buffer (coalesced global loads + broadcast ds_reads, off the TCP
// pipe); high occupancy (no big LDS slice), idx stream read exactly once.
__global__ __launch_bounds__(256) void clause_tcp(const uint4* __restrict__ xf4,
                                                  const int* __restrict__ I,
                                                  float* __restrict__ out) {
    __shared__ int4 ibuf[TGB * 7];                    // 7 KB, row-padded (bank spread)
    const int tid = threadIdx.x;
    const int c = blockIdx.y;
    const int g0 = blockIdx.x * TGB;

    // Stage this block's indices: 64 g x 6 int4 = 384 int4, consecutive.
    const int4* Ib = (const int4*)(I + ((size_t)c * Gg + g0) * (Ss * Ll));
    {
        int4 v0 = Ib[tid];
        ibuf[(tid / 6) * 7 + (tid % 6)] = v0;
        int t1 = 256 + tid;
        if (t1 < TGB * 6) {
            int4 v1 = Ib[t1];
            ibuf[(t1 / 6) * 7 + (t1 % 6)] = v1;
        }
    }
    __syncthreads();

    const int part = tid & 3;
    const int gl = tid >> 2;                           // 0..63
    const int g = g0 + gl;

    int idx[Ss * Ll];
    #pragma unroll
    for (int k = 0; k < 6; ++k) {
        int4 v = ibuf[gl * 7 + k];                     // 4-lane broadcast reads
        idx[4 * k + 0] = v.x; idx[4 * k + 1] = v.y;
        idx[4 * k + 2] = v.z; idx[4 * k + 3] = v.w;
    }

    // 24 independent random-line gathers, max MLP.
    uint4 vv[Ss * Ll];
    #pragma unroll
    for (int k = 0; k < Ss * Ll; ++k)
        vv[k] = xf4[(idx[k] << 2) | part];             // row idx, 16 B chunk `part`

    float acc[8] = {0.f, 0.f, 0.f, 0.f, 0.f, 0.f, 0.f, 0.f};
    #pragma unroll
    for (int s = 0; s < Ss; ++s) {
        const __half2* a = (const __half2*)&vv[3 * s];
        const __half2* b = (const __half2*)&vv[3 * s + 1];
        const __half2* d = (const __half2*)&vv[3 * s + 2];
        #pragma unroll
        for (int j = 0; j < 4; ++j) {
            __half2 p = __hmul2(__hmul2(a[j], b[j]), d[j]);   // v_pk_mul_f16
            float2 pf = __half22float2(p);
            acc[2 * j]     += pf.x;
            acc[2 * j + 1] += pf.y;
        }
    }

    // b = 8*part + j. Per store instr: 4 b-rows x 16 consecutive g = 4 lines.
    float* op = out + ((size_t)(c * Bb + 8 * part)) * Gg + g;
    #pragma unroll
    for (int j = 0; j < 8; ++j)
        op[(size_t)j * Gg] = acc[j];
}

// --- Fallback (ws too small): direct global gather; slow but correct.
__global__ __launch_bounds__(256) void clause_kernel_direct(const float* __restrict__ x,
                                                            const int* __restrict__ I,
                                                            float* __restrict__ out) {
    const int tid = threadIdx.x;
    const int b = tid & 31;
    const int j = tid >> 5;
    const int g = blockIdx.x * 8 + j;
    const int c = blockIdx.y;

    const int* Icg = I + (size_t)(c * Gg + g) * (Ss * Ll);
    float sum = 0.f;
    #pragma unroll
    for (int s = 0; s < Ss; ++s) {
        float p0 = x[(size_t)b * Gg + Icg[3 * s + 0]];
        float p1 = x[(size_t)b * Gg + Icg[3 * s + 1]];
        float p2 = x[(size_t)b * Gg + Icg[3 * s + 2]];
        sum += p0 * p1 * p2;
    }
    out[(size_t)(c * Bb + b) * Gg + g] = sum;
}

extern "C" void kernel_launch(void* const* d_in, const int* in_sizes, int n_in,
                              void* d_out, int out_size, void* d_ws, size_t ws_size,
                              hipStream_t stream) {
    const float* x = (const float*)d_in[0];
    const int* I = (const int*)d_in[1];
    float* out = (float*)d_out;

    const size_t xf_bytes = (size_t)Gg * 64;           // 512 KB

    if (ws_size >= xf_bytes) {
        uint2* xf2 = (uint2*)d_ws;
        build_xf<<<Gg / 32, 256, 0, stream>>>(x, xf2);
        clause_tcp<<<dim3(Gg / TGB, Cc), 256, 0, stream>>>((const uint4*)xf2, I, out);
    } else {
        clause_kernel_direct<<<dim3(Gg / 8, Cc), 256, 0, stream>>>(x, I, out);
    }
}

// Round 10
// 81.644 us; speedup vs baseline: 1.0328x; 1.0328x over previous
//
#include <hip/hip_runtime.h>
#include <hip/hip_fp16.h>
#include <stdint.h>

// out[c,b,g] = sum_{s<8} prod_{l<3} x[b, I[c,g,s,l]]
#define Cc 16
#define Gg 8192
#define Ss 8
#define Ll 3
#define Bb 32

#define ZS 4               // b-oct slices (f16): slice z holds b = 8z .. 8z+7
#define THREADS 512
#define ITERS 2            // (c,g) per thread per block

// --- Kernel A: xh[z][g] = 8 f16 (b = 8z..8z+7), two 8 B halves SWAPPED when
// s(g) = (g>>3)&1; reader undoes the swap in the address (R8 layout, kept).
__global__ __launch_bounds__(256) void build_xh(const float* __restrict__ x,
                                                uint4* __restrict__ xh) {
    int t = blockIdx.x * 256 + threadIdx.x;        // over ZS*Gg
    int z = t >> 13;
    int g = t & (Gg - 1);
    uint32_t d[4];
    #pragma unroll
    for (int j = 0; j < 4; ++j) {
        __half2 h = __floats2half2_rn(x[(size_t)(8 * z + 2 * j) * Gg + g],
                                      x[(size_t)(8 * z + 2 * j + 1) * Gg + g]);
        d[j] = *(const uint32_t*)&h;
    }
    uint32_t s = (g >> 3) & 1u;
    xh[t] = s ? make_uint4(d[2], d[3], d[0], d[1])
              : make_uint4(d[0], d[1], d[2], d[3]);
}

// Evaluate one (c,g): 24 indices in q[6], gathers from the swizzled LDS image.
__device__ __forceinline__ void clause_eval(const uint2* __restrict__ xl2,
                                            const int4 q[6], float acc[8]) {
    int idx[Ss * Ll] = {q[0].x, q[0].y, q[0].z, q[0].w, q[1].x, q[1].y, q[1].z, q[1].w,
                        q[2].x, q[2].y, q[2].z, q[2].w, q[3].x, q[3].y, q[3].z, q[3].w,
                        q[4].x, q[4].y, q[4].z, q[4].w, q[5].x, q[5].y, q[5].z, q[5].w};
    uint2 r0[Ss * Ll], r1[Ss * Ll];
    #pragma unroll
    for (int k = 0; k < Ss * Ll; ++k) {            // 48 independent ds_read_b64
        uint32_t u = (uint32_t)idx[k];
        uint32_t a0 = (u << 1) | ((u >> 3) & 1u);  // swizzle undone by address
        r0[k] = xl2[a0];                           // b 0..3 (f16 pairs)
        r1[k] = xl2[a0 ^ 1u];                      // b 4..7
    }
    #pragma unroll
    for (int s = 0; s < Ss; ++s) {
        const int k0 = 3 * s, k1 = 3 * s + 1, k2 = 3 * s + 2;
        const uint32_t pa[4] = {r0[k0].x, r0[k0].y, r1[k0].x, r1[k0].y};
        const uint32_t pb[4] = {r0[k1].x, r0[k1].y, r1[k1].x, r1[k1].y};
        const uint32_t pd[4] = {r0[k2].x, r0[k2].y, r1[k2].x, r1[k2].y};
        #pragma unroll
        for (int j = 0; j < 4; ++j) {
            __half2 a = *(const __half2*)&pa[j];
            __half2 b = *(const __half2*)&pb[j];
            __half2 d = *(const __half2*)&pd[j];
            __half2 p = __hmul2(__hmul2(a, b), d);   // v_pk_mul_f16 x2
            float2 pf = __half22float2(p);
            acc[2 * j] += pf.x;
            acc[2 * j + 1] += pf.y;
        }
    }
}

// --- Kernel B: stage one f16-oct slice (128 KB, all G) once per block via
// PLAIN vector loads + ds_write (NOT global_load_lds: the async DMA does not
// pipeline deeply enough — it was the hidden ~20 us in R6-R8). Then each
// thread evaluates ITERS (c,g) clauses with 2xb64 swizzled gathers.
__global__ __launch_bounds__(THREADS) void clause_f16(const uint4* __restrict__ xh,
                                                      const int* __restrict__ I,
                                                      float* __restrict__ out) {
    __shared__ uint4 xl[Gg];                       // 128 KB
    const int tid = threadIdx.x;
    const int z = blockIdx.y;
    const int c = blockIdx.x >> 3;                 // 8 blocks per c
    const int gbase = (blockIdx.x & 7) * (THREADS * ITERS);

    // Stage slice z: 16 x 16 B per thread, two deep-MLP chunks of 8.
    // Loads are lane-consecutive (coalesced); ds_write_b128 conflict-free.
    {
        const uint4* gs = xh + (size_t)z * Gg;
        uint4 t0[8];
        #pragma unroll
        for (int i = 0; i < 8; ++i) t0[i] = gs[tid + i * THREADS];
        #pragma unroll
        for (int i = 0; i < 8; ++i) xl[tid + i * THREADS] = t0[i];
        uint4 t1[8];
        #pragma unroll
        for (int i = 0; i < 8; ++i) t1[i] = gs[tid + (8 + i) * THREADS];
        #pragma unroll
        for (int i = 0; i < 8; ++i) xl[tid + (8 + i) * THREADS] = t1[i];
    }

    // Prefetch both iterations' raw int32 indices (vmcnt path, overlaps stage).
    const int g0 = gbase + tid;
    const int g1 = gbase + THREADS + tid;
    const int4* ip0 = (const int4*)(I + ((size_t)c * Gg + g0) * (Ss * Ll));
    const int4* ip1 = (const int4*)(I + ((size_t)c * Gg + g1) * (Ss * Ll));
    int4 q0[6], q1[6];
    #pragma unroll
    for (int k = 0; k < 6; ++k) q0[k] = ip0[k];
    #pragma unroll
    for (int k = 0; k < 6; ++k) q1[k] = ip1[k];

    __syncthreads();                               // the ONE barrier

    const uint2* xl2 = (const uint2*)xl;
    float* opb = out + ((size_t)(c * Bb + 8 * z)) * Gg;

    {
        float acc[8] = {0, 0, 0, 0, 0, 0, 0, 0};
        clause_eval(xl2, q0, acc);
        #pragma unroll
        for (int j = 0; j < 8; ++j)                // 64 consecutive g -> coalesced
            opb[(size_t)j * Gg + g0] = acc[j];
    }
    {
        float acc[8] = {0, 0, 0, 0, 0, 0, 0, 0};
        clause_eval(xl2, q1, acc);
        #pragma unroll
        for (int j = 0; j < 8; ++j)
            opb[(size_t)j * Gg + g1] = acc[j];
    }
}

// --- Fallback (ws too small): direct global gather; slow but correct.
__global__ __launch_bounds__(256) void clause_kernel_direct(const float* __restrict__ x,
                                                            const int* __restrict__ I,
                                                            float* __restrict__ out) {
    const int tid = threadIdx.x;
    const int b = tid & 31;
    const int j = tid >> 5;
    const int g = blockIdx.x * 8 + j;
    const int c = blockIdx.y;

    const int* Icg = I + (size_t)(c * Gg + g) * (Ss * Ll);
    float sum = 0.f;
    #pragma unroll
    for (int s = 0; s < Ss; ++s) {
        float p0 = x[(size_t)b * Gg + Icg[3 * s + 0]];
        float p1 = x[(size_t)b * Gg + Icg[3 * s + 1]];
        float p2 = x[(size_t)b * Gg + Icg[3 * s + 2]];
        sum += p0 * p1 * p2;
    }
    out[(size_t)(c * Bb + b) * Gg + g] = sum;
}

extern "C" void kernel_launch(void* const* d_in, const int* in_sizes, int n_in,
                              void* d_out, int out_size, void* d_ws, size_t ws_size,
                              hipStream_t stream) {
    const float* x = (const float*)d_in[0];
    const int* I = (const int*)d_in[1];
    float* out = (float*)d_out;

    const size_t xh_bytes = (size_t)ZS * Gg * sizeof(uint4);  // 512 KB

    if (ws_size >= xh_bytes) {
        uint4* xh = (uint4*)d_ws;
        build_xh<<<(ZS * Gg) / 256, 256, 0, stream>>>(x, xh);
        clause_f16<<<dim3((Cc * Gg) / (THREADS * ITERS), ZS), THREADS, 0, stream>>>(xh, I, out);
    } else {
        clause_kernel_direct<<<dim3(Gg / 8, Cc), 256, 0, stream>>>(x, I, out);
    }
}